// Round 11
// baseline (350.607 us; speedup 1.0000x reference)
//
#include <hip/hip_runtime.h>
#include <stdint.h>

#define TT 256
#define II 6
#define HH 64
#define MB 16   // batches per block (one 16-wide MFMA N-tile)

typedef __attribute__((ext_vector_type(8))) _Float16 half8;
typedef __attribute__((ext_vector_type(4))) float f32x4;

#define K_LOG2E  1.44269504f
#define K_2LOG2E 2.88539008f

// raw barrier: LDS visibility only (x prefetch loads may span barriers)
#define BAR() asm volatile("s_waitcnt lgkmcnt(0)\n\ts_barrier" ::: "memory")

static __device__ __forceinline__ uint32_t pkh(float a, float b){
    uint16_t ha = __builtin_bit_cast(uint16_t, (_Float16)a);
    uint16_t hb = __builtin_bit_cast(uint16_t, (_Float16)b);
    return (uint32_t)ha | ((uint32_t)hb << 16);
}
static __device__ __forceinline__ uint32_t pkrtz(float a, float b){
    return __builtin_bit_cast(uint32_t, __builtin_amdgcn_cvt_pkrtz(a, b));
}
static __device__ __forceinline__ half8 mkh8(uint32_t a, uint32_t b, uint32_t c, uint32_t d){
    union { uint32_t u[4]; half8 v; } x;
    x.u[0]=a; x.u[1]=b; x.u[2]=c; x.u[3]=d;
    return x.v;
}
static __device__ __forceinline__ half8 ldq(const uint32_t* p){
    union { uint4 q; half8 v; } x;
    x.q = *(const uint4*)p;
    return x.v;
}
static __device__ __forceinline__ f32x4 MFi(half8 A, half8 B, f32x4 C){
    return __builtin_amdgcn_mfma_f32_16x16x32_f16(A, B, C, 0, 0, 0);
}
union U4F { uint4 u; f32x4 f; };

// sigma part (rz-wave): identical op sequence to v9's gates() head -> bit-identical
static __device__ __forceinline__ void sigma_store(const f32x4& Cr, const f32x4& Cz,
                                                   uint4* pR, uint4* pZ){
    U4F rg, zg;
    #pragma unroll
    for (int q = 0; q < 4; ++q){
        float er = __builtin_amdgcn_exp2f(-Cr[q]);
        float ez = __builtin_amdgcn_exp2f(-Cz[q]);
        float pa = 1.0f + er, pb = 1.0f + ez;
        float u  = __builtin_amdgcn_rcpf(pa * pb);
        rg.f[q] = u * pb;
        zg.f[q] = u * pa;
    }
    *pR = rg.u; *pZ = zg.u;
}
// tanh + h-update (n-wave): identical tail to v9's gates()
static __device__ __forceinline__ uint2 finish_n(const f32x4& Cxn, const f32x4& Chn,
                                                 uint4 rgu, uint4 zgu, f32x4& hp){
    U4F rg, zg; rg.u = rgu; zg.u = zgu;
    float num[4], den[4];
    #pragma unroll
    for (int q = 0; q < 4; ++q){
        float v = Cxn[q] + rg.f[q] * Chn[q];
        float e = __builtin_amdgcn_exp2f(-v);
        num[q] = 1.0f - e;
        den[q] = 1.0f + e;
    }
    float hn[4];
    #pragma unroll
    for (int pr = 0; pr < 2; ++pr){
        const int q0 = 2*pr, q1 = 2*pr + 1;
        float t  = __builtin_amdgcn_rcpf(den[q0] * den[q1]);
        float n0 = num[q0] * (t * den[q1]);
        float n1 = num[q1] * (t * den[q0]);
        float h0 = n0 + zg.f[q0] * (hp[q0] - n0);
        float h1 = n1 + zg.f[q1] * (hp[q1] - n1);
        hp[q0] = h0; hp[q1] = h1;
        hn[q0] = h0; hn[q1] = h1;
    }
    return make_uint2(pkrtz(hn[0], hn[1]), pkrtz(hn[2], hn[3]));
}

__global__ __launch_bounds__(1024, 4)
void gru2_v11(const float* __restrict__ x,
              const float* __restrict__ Wih0, const float* __restrict__ Whh0,
              const float* __restrict__ bih0, const float* __restrict__ bhh0,
              const float* __restrict__ Wih1, const float* __restrict__ Whh1,
              const float* __restrict__ bih1, const float* __restrict__ bhh1,
              const float* __restrict__ Wfc,  const float* __restrict__ bfc,
              float* __restrict__ out)
{
    __shared__ uint32_t h0buf[2][MB][36];   // h exchange (fp16 pairs + pad)
    __shared__ uint32_t h1buf[2][MB][36];
    __shared__ uint4    rgb[2][4][64];      // sigma(r) handoff f32x4 [layer][tile][lane]
    __shared__ uint4    zgb[2][4][64];      // sigma(z)
    __shared__ float    fcpart[16][MB];

    const int tid   = threadIdx.x;
    const int lane  = tid & 63;
    const int wg    = tid >> 6;        // 0..15
    const int layer = wg >> 3;         // 0,1
    const int role  = (wg >> 2) & 1;   // 0 = rz, 1 = n
    const int w     = wg & 3;          // gate-tile
    const int c     = lane >> 4;
    const int r16   = lane & 15;
    const int b0    = blockIdx.x * MB;

    for (int i = tid; i < 2 * MB * 36; i += 1024){
        (&h0buf[0][0][0])[i] = 0u;
        (&h1buf[0][0][0])[i] = 0u;
    }

    // ---- per-role weights (fp16, pre-scaled) ----
    half8 WA[2][2];   // rz: [gate r/z][chunk]  (L0: Whh0, L1: Wih1)
    half8 WB[2][2];   // rz L1: Whh1
    half8 WN1[2];     // n: L0: Whh0_n  / L1: Wih1_n
    half8 WN2[2];     // n L1: Whh1_n
    half8 AxA[2], AxN;// L0 x-weights
    f32x4 B1, B2;     // rz: Br,Bz ; n: Bxn,Bhn

    const int rq0 = w * 16 + c * 4;
    const float* bi = layer ? bih1 : bih0;
    const float* bh = layer ? bhh1 : bhh0;
    if (role == 0){
        const float* Wp = layer ? Wih1 : Whh0;
        #pragma unroll
        for (int g = 0; g < 2; ++g){
            const float* rowp = Wp + (size_t)(g * 64 + w * 16 + r16) * HH;
            #pragma unroll
            for (int cw = 0; cw < 2; ++cw){
                const float* pp = rowp + cw * 32 + c * 8;
                WA[g][cw] = mkh8(pkh(K_LOG2E*pp[0], K_LOG2E*pp[1]),
                                 pkh(K_LOG2E*pp[2], K_LOG2E*pp[3]),
                                 pkh(K_LOG2E*pp[4], K_LOG2E*pp[5]),
                                 pkh(K_LOG2E*pp[6], K_LOG2E*pp[7]));
            }
        }
        if (layer){
            #pragma unroll
            for (int g = 0; g < 2; ++g){
                const float* rowp = Whh1 + (size_t)(g * 64 + w * 16 + r16) * HH;
                #pragma unroll
                for (int cw = 0; cw < 2; ++cw){
                    const float* pp = rowp + cw * 32 + c * 8;
                    WB[g][cw] = mkh8(pkh(K_LOG2E*pp[0], K_LOG2E*pp[1]),
                                     pkh(K_LOG2E*pp[2], K_LOG2E*pp[3]),
                                     pkh(K_LOG2E*pp[4], K_LOG2E*pp[5]),
                                     pkh(K_LOG2E*pp[6], K_LOG2E*pp[7]));
                }
            }
        } else {
            #pragma unroll
            for (int g = 0; g < 2; ++g){
                if (c == 0){
                    const float* rowp = Wih0 + (size_t)(g * 64 + w * 16 + r16) * II;
                    AxA[g] = mkh8(pkh(K_LOG2E*rowp[0], K_LOG2E*rowp[1]),
                                  pkh(K_LOG2E*rowp[2], K_LOG2E*rowp[3]),
                                  pkh(K_LOG2E*rowp[4], K_LOG2E*rowp[5]), 0u);
                } else AxA[g] = mkh8(0u,0u,0u,0u);
            }
        }
        #pragma unroll
        for (int q = 0; q < 4; ++q){
            B1[q] = K_LOG2E * (bi[     rq0 + q] + bh[     rq0 + q]);  // Br
            B2[q] = K_LOG2E * (bi[64 + rq0 + q] + bh[64 + rq0 + q]);  // Bz
        }
    } else {
        const float* Wp = layer ? Wih1 : Whh0;
        {
            const float* rowp = Wp + (size_t)(128 + w * 16 + r16) * HH;
            #pragma unroll
            for (int cw = 0; cw < 2; ++cw){
                const float* pp = rowp + cw * 32 + c * 8;
                WN1[cw] = mkh8(pkh(K_2LOG2E*pp[0], K_2LOG2E*pp[1]),
                               pkh(K_2LOG2E*pp[2], K_2LOG2E*pp[3]),
                               pkh(K_2LOG2E*pp[4], K_2LOG2E*pp[5]),
                               pkh(K_2LOG2E*pp[6], K_2LOG2E*pp[7]));
            }
        }
        if (layer){
            const float* rowp = Whh1 + (size_t)(128 + w * 16 + r16) * HH;
            #pragma unroll
            for (int cw = 0; cw < 2; ++cw){
                const float* pp = rowp + cw * 32 + c * 8;
                WN2[cw] = mkh8(pkh(K_2LOG2E*pp[0], K_2LOG2E*pp[1]),
                               pkh(K_2LOG2E*pp[2], K_2LOG2E*pp[3]),
                               pkh(K_2LOG2E*pp[4], K_2LOG2E*pp[5]),
                               pkh(K_2LOG2E*pp[6], K_2LOG2E*pp[7]));
            }
        } else {
            if (c == 0){
                const float* rowp = Wih0 + (size_t)(128 + w * 16 + r16) * II;
                AxN = mkh8(pkh(K_2LOG2E*rowp[0], K_2LOG2E*rowp[1]),
                           pkh(K_2LOG2E*rowp[2], K_2LOG2E*rowp[3]),
                           pkh(K_2LOG2E*rowp[4], K_2LOG2E*rowp[5]), 0u);
            } else AxN = mkh8(0u,0u,0u,0u);
        }
        #pragma unroll
        for (int q = 0; q < 4; ++q){
            B1[q] = K_2LOG2E * bi[128 + rq0 + q];   // Bxn
            B2[q] = K_2LOG2E * bh[128 + rq0 + q];   // Bhn
        }
    }

    // pointers
    const uint32_t* rd0[2] = { &h0buf[0][r16][4*c], &h0buf[1][r16][4*c] };
    const uint32_t* rd1[2] = { &h1buf[0][r16][4*c], &h1buf[1][r16][4*c] };
    uint32_t* hwr = layer ? &h1buf[0][r16][8*w + 2*c] : &h0buf[0][r16][8*w + 2*c];
    uint2* wrp[2] = { (uint2*)hwr, (uint2*)(hwr + MB*36) };
    uint4* sgR = &rgb[layer][w][lane];
    uint4* sgZ = &zgb[layer][w][lane];

    f32x4 hp  = {0.f,0.f,0.f,0.f};          // n-waves: fp32 h carry
    f32x4 Pr  = {0.f,0.f,0.f,0.f}, Pz = Pr, Pxn = Pr;   // L0 x-part preps
    f32x4 Cxn = Pr, Chn = Pr;               // n-waves: carried A->B

    const float* xq = nullptr;
    float2 x0v = make_float2(0.f,0.f), x1v = x0v, x2v = x0v;
    if (layer == 0){
        xq = x + (size_t)(b0 + r16) * (TT * II);
        float2 a  = *(const float2*)(xq + 0);
        float2 bb = *(const float2*)(xq + 2);
        float2 cc = *(const float2*)(xq + 4);
        half8 XB = mkh8(pkrtz(a.x, a.y), pkrtz(bb.x, bb.y), pkrtz(cc.x, cc.y), 0u);
        if (role == 0){ Pr = MFi(AxA[0], XB, B1); Pz = MFi(AxA[1], XB, B2); }
        else          { Pxn = MFi(AxN, XB, B1); }
        xq += II;
        x0v = *(const float2*)(xq + 0);
        x1v = *(const float2*)(xq + 2);
        x2v = *(const float2*)(xq + 4);
    }
    __syncthreads();

#define PHA(P, TK) do {                                                             \
    if (layer == 0){ if ((TK) < TT){                                                \
        half8 H0 = ldq(rd0[P]); half8 H1 = ldq(rd0[P] + 16);                        \
        if (role == 0){                                                             \
            __builtin_amdgcn_s_setprio(1);                                          \
            f32x4 Cr = MFi(WA[0][0], H0, Pr); Cr = MFi(WA[0][1], H1, Cr);           \
            f32x4 Cz = MFi(WA[1][0], H0, Pz); Cz = MFi(WA[1][1], H1, Cz);           \
            __builtin_amdgcn_s_setprio(0);                                          \
            sigma_store(Cr, Cz, sgR, sgZ);                                          \
        } else {                                                                    \
            __builtin_amdgcn_s_setprio(1);                                          \
            Chn = MFi(WN1[0], H0, B2); Chn = MFi(WN1[1], H1, Chn);                  \
            __builtin_amdgcn_s_setprio(0);                                          \
            Cxn = Pxn;                                                              \
        }                                                                           \
    }} else { if ((TK) >= 1){                                                       \
        half8 G0 = ldq(rd0[P]); half8 G1 = ldq(rd0[P] + 16);                        \
        half8 H0 = ldq(rd1[P]); half8 H1 = ldq(rd1[P] + 16);                        \
        if (role == 0){                                                             \
            __builtin_amdgcn_s_setprio(1);                                          \
            f32x4 Cr = MFi(WA[0][0], G0, B1); Cr = MFi(WA[0][1], G1, Cr);           \
            Cr = MFi(WB[0][0], H0, Cr);       Cr = MFi(WB[0][1], H1, Cr);           \
            f32x4 Cz = MFi(WA[1][0], G0, B2); Cz = MFi(WA[1][1], G1, Cz);           \
            Cz = MFi(WB[1][0], H0, Cz);       Cz = MFi(WB[1][1], H1, Cz);           \
            __builtin_amdgcn_s_setprio(0);                                          \
            sigma_store(Cr, Cz, sgR, sgZ);                                          \
        } else {                                                                    \
            __builtin_amdgcn_s_setprio(1);                                          \
            Cxn = MFi(WN1[0], G0, B1); Cxn = MFi(WN1[1], G1, Cxn);                  \
            Chn = MFi(WN2[0], H0, B2); Chn = MFi(WN2[1], H1, Chn);                  \
            __builtin_amdgcn_s_setprio(0);                                          \
        }                                                                           \
    }}                                                                              \
} while(0)

#define PHB(P, TK) do {                                                             \
    if (role == 1){                                                                 \
        const bool act = (layer == 0) ? ((TK) < TT) : ((TK) >= 1);                  \
        if (act){                                                                   \
            uint4 rgu = *sgR; uint4 zgu = *sgZ;                                     \
            uint2 d = finish_n(Cxn, Chn, rgu, zgu, hp);                             \
            *wrp[(P) ^ 1] = d;                                                      \
        }                                                                           \
        if (layer == 0 && (TK) + 1 < TT){                                           \
            half8 XB = mkh8(pkrtz(x0v.x, x0v.y), pkrtz(x1v.x, x1v.y),               \
                            pkrtz(x2v.x, x2v.y), 0u);                               \
            Pxn = MFi(AxN, XB, B1);                                                 \
            if ((TK) + 2 < TT){                                                     \
                xq += II;                                                           \
                x0v = *(const float2*)(xq + 0);                                     \
                x1v = *(const float2*)(xq + 2);                                     \
                x2v = *(const float2*)(xq + 4);                                     \
            }                                                                       \
        }                                                                           \
    } else {                                                                        \
        if (layer == 0 && (TK) + 1 < TT){                                           \
            half8 XB = mkh8(pkrtz(x0v.x, x0v.y), pkrtz(x1v.x, x1v.y),               \
                            pkrtz(x2v.x, x2v.y), 0u);                               \
            Pr = MFi(AxA[0], XB, B1);                                               \
            Pz = MFi(AxA[1], XB, B2);                                               \
            if ((TK) + 2 < TT){                                                     \
                xq += II;                                                           \
                x0v = *(const float2*)(xq + 0);                                     \
                x1v = *(const float2*)(xq + 2);                                     \
                x2v = *(const float2*)(xq + 4);                                     \
            }                                                                       \
        }                                                                           \
    }                                                                               \
} while(0)

    // tick 0 (P=0): L0 only
    PHA(0, 0);  BAR();
    PHB(0, 0);  BAR();
    #pragma unroll 1
    for (int tk = 1; tk < 255; tk += 2){
        PHA(1, tk);     BAR();
        PHB(1, tk);     BAR();
        PHA(0, tk + 1); BAR();
        PHB(0, tk + 1); BAR();
    }
    PHA(1, 255); BAR();
    PHB(1, 255); BAR();
    PHA(0, 256); BAR();
    PHB(0, 256);            // L1 finishes h1(255)

#undef PHA
#undef PHB

    // ---- final FC: out[b] = dot(h1_final[b], Wfc) + bfc  (h1 carry in L1 n-waves)
    if (layer == 1 && role == 1){
        float4 wf = *(const float4*)(Wfc + w * 16 + c * 4);
        fcpart[w * 4 + c][r16] =
            hp[0] * wf.x + hp[1] * wf.y + hp[2] * wf.z + hp[3] * wf.w;
    }
    __syncthreads();
    if (tid < MB){
        float s = bfc[0];
        #pragma unroll
        for (int k = 0; k < 16; ++k) s += fcpart[k][tid];
        out[b0 + tid] = s;
    }
}

extern "C" void kernel_launch(void* const* d_in, const int* in_sizes, int n_in,
                              void* d_out, int out_size, void* d_ws, size_t ws_size,
                              hipStream_t stream)
{
    const float* x    = (const float*)d_in[0];
    const float* Wih0 = (const float*)d_in[1];
    const float* Whh0 = (const float*)d_in[2];
    const float* bih0 = (const float*)d_in[3];
    const float* bhh0 = (const float*)d_in[4];
    const float* Wih1 = (const float*)d_in[5];
    const float* Whh1 = (const float*)d_in[6];
    const float* bih1 = (const float*)d_in[7];
    const float* bhh1 = (const float*)d_in[8];
    const float* Wfc  = (const float*)d_in[9];
    const float* bfc  = (const float*)d_in[10];
    float* out = (float*)d_out;

    dim3 grid(4096 / MB), block(1024);
    gru2_v11<<<grid, block, 0, stream>>>(x, Wih0, Whh0, bih0, bhh0,
                                         Wih1, Whh1, bih1, bhh1,
                                         Wfc, bfc, out);
}

// Round 12
// 141.203 us; speedup vs baseline: 2.4830x; 2.4830x over previous
//
#include <hip/hip_runtime.h>
#include <stdint.h>

#define TT 256
#define II 6
#define HH 64
#define MB 16   // batches per block (one 16-wide MFMA N-tile)

typedef __attribute__((ext_vector_type(8))) _Float16 half8;
typedef __attribute__((ext_vector_type(4))) float f32x4;

#define K_LOG2E  1.44269504f
#define K_2LOG2E 2.88539008f

// raw barrier: LDS visibility only (x prefetch loads may span barriers)
#define BAR() asm volatile("s_waitcnt lgkmcnt(0)\n\ts_barrier" ::: "memory")

static __device__ __forceinline__ uint32_t pkh(float a, float b){
    uint16_t ha = __builtin_bit_cast(uint16_t, (_Float16)a);
    uint16_t hb = __builtin_bit_cast(uint16_t, (_Float16)b);
    return (uint32_t)ha | ((uint32_t)hb << 16);
}
static __device__ __forceinline__ uint32_t pkrtz(float a, float b){
    return __builtin_bit_cast(uint32_t, __builtin_amdgcn_cvt_pkrtz(a, b));
}
static __device__ __forceinline__ half8 mkh8(uint32_t a, uint32_t b, uint32_t c, uint32_t d){
    union { uint32_t u[4]; half8 v; } x;
    x.u[0]=a; x.u[1]=b; x.u[2]=c; x.u[3]=d;
    return x.v;
}
static __device__ __forceinline__ half8 ldq(const uint32_t* p){
    union { uint4 q; half8 v; } x;
    x.q = *(const uint4*)p;
    return x.v;
}
static __device__ __forceinline__ f32x4 MFi(half8 A, half8 B, f32x4 C){
    return __builtin_amdgcn_mfma_f32_16x16x32_f16(A, B, C, 0, 0, 0);
}

// Pre-activations pre-scaled (r,z by log2e; n by 2log2e):
// sigma(a)=1/(1+exp2(-C)), tanh(v)=(1-exp2(-v'))/(1+exp2(-v')).
static __device__ __forceinline__ uint2 gates(const f32x4& Cr, const f32x4& Cz,
                                              const f32x4& Cxn, const f32x4& Chn,
                                              f32x4& hp)
{
    float num[4], den[4], zg4[4];
    #pragma unroll
    for (int q = 0; q < 4; ++q){
        float er = __builtin_amdgcn_exp2f(-Cr[q]);
        float ez = __builtin_amdgcn_exp2f(-Cz[q]);
        float pa = 1.0f + er, pb = 1.0f + ez;
        float u  = __builtin_amdgcn_rcpf(pa * pb);
        float rg = u * pb;                      // sigma(r)
        zg4[q]   = u * pa;                      // sigma(z)
        float v  = Cxn[q] + rg * Chn[q];
        float e  = __builtin_amdgcn_exp2f(-v);
        num[q] = 1.0f - e;
        den[q] = 1.0f + e;
    }
    float hn[4];
    #pragma unroll
    for (int pr = 0; pr < 2; ++pr){
        const int q0 = 2*pr, q1 = 2*pr + 1;
        float t  = __builtin_amdgcn_rcpf(den[q0] * den[q1]);
        float n0 = num[q0] * (t * den[q1]);
        float n1 = num[q1] * (t * den[q0]);
        float h0 = n0 + zg4[q0] * (hp[q0] - n0);
        float h1 = n1 + zg4[q1] * (hp[q1] - n1);
        hp[q0] = h0; hp[q1] = h1;
        hn[q0] = h0; hn[q1] = h1;
    }
    return make_uint2(pkrtz(hn[0], hn[1]), pkrtz(hn[2], hn[3]));
}

__global__ __launch_bounds__(512, 2)
void gru2_v12(const float* __restrict__ x,
              const float* __restrict__ Wih0, const float* __restrict__ Whh0,
              const float* __restrict__ bih0, const float* __restrict__ bhh0,
              const float* __restrict__ Wih1, const float* __restrict__ Whh1,
              const float* __restrict__ bih1, const float* __restrict__ bhh1,
              const float* __restrict__ Wfc,  const float* __restrict__ bfc,
              float* __restrict__ out)
{
    __shared__ uint32_t h0buf[2][MB][36];   // [parity][batch][h/2 dwords + pad]
    __shared__ uint32_t h1buf[2][MB][36];
    __shared__ float    fcpart[16][MB];

    const int tid  = threadIdx.x;
    const int lane = tid & 63;
    const int wg   = tid >> 6;       // 0..7
    const int isL1 = (wg >= 4);      // waves 4..7 run layer 1 (lagged one tick)
    const int w    = wg & 3;         // 16-row tile within each gate
    const int c    = lane >> 4;      // k-group / C row-group
    const int r16  = lane & 15;      // batch col
    const int b0   = blockIdx.x * MB;

    for (int i = tid; i < 2 * MB * 36; i += 512){
        (&h0buf[0][0][0])[i] = 0u;
        (&h1buf[0][0][0])[i] = 0u;
    }

    // ---- A-fragments (fp16, pre-scaled by {log2e, log2e, 2log2e}) ----
    const float gsc[3] = { K_LOG2E, K_LOG2E, K_2LOG2E };
    half8 AW[6][2];
    {
        const float* M0 = isL1 ? Wih1 : Whh0;
        #pragma unroll
        for (int m = 0; m < 6; ++m){
            if (m >= 3 && !isL1) continue;
            const float* Wb = (m < 3) ? M0 : Whh1;
            const float s = gsc[m % 3];
            const float* rowp = Wb + (size_t)((m % 3) * 64 + w * 16 + r16) * HH;
            #pragma unroll
            for (int cw = 0; cw < 2; ++cw){
                const float* pp = rowp + cw * 32 + c * 8;
                AW[m][cw] = mkh8(pkh(s*pp[0], s*pp[1]), pkh(s*pp[2], s*pp[3]),
                                 pkh(s*pp[4], s*pp[5]), pkh(s*pp[6], s*pp[7]));
            }
        }
    }
    half8 Ax[3];
    #pragma unroll
    for (int g = 0; g < 3; ++g){
        if (c == 0 && !isL1){
            const float s = gsc[g];
            const float* rowp = Wih0 + (size_t)(g * 64 + w * 16 + r16) * II;
            Ax[g] = mkh8(pkh(s*rowp[0], s*rowp[1]), pkh(s*rowp[2], s*rowp[3]),
                         pkh(s*rowp[4], s*rowp[5]), 0u);
        } else {
            Ax[g] = mkh8(0u, 0u, 0u, 0u);
        }
    }

    // biases (pre-scaled): row = g*64 + w*16 + 4c + q
    const float* bi = isL1 ? bih1 : bih0;
    const float* bh = isL1 ? bhh1 : bhh0;
    const int rq0 = w * 16 + c * 4;
    f32x4 Br, Bz, Bxn, Bhn;
    #pragma unroll
    for (int q = 0; q < 4; ++q){
        Br[q]  = K_LOG2E  * (bi[      rq0 + q] + bh[      rq0 + q]);
        Bz[q]  = K_LOG2E  * (bi[ 64 + rq0 + q] + bh[ 64 + rq0 + q]);
        Bxn[q] = K_2LOG2E *  bi[128 + rq0 + q];
        Bhn[q] = K_2LOG2E *  bh[128 + rq0 + q];
    }
    const f32x4 Zed = {0.f, 0.f, 0.f, 0.f};

    f32x4 hp = {0.f, 0.f, 0.f, 0.f};   // fp32 carry of own h slice

    // hoisted per-parity LDS pointers
    const uint32_t* rd0[2] = { &h0buf[0][r16][4*c], &h0buf[1][r16][4*c] };
    const uint32_t* rd1[2] = { &h1buf[0][r16][4*c], &h1buf[1][r16][4*c] };
    uint2* wr0[2] = { (uint2*)&h0buf[0][r16][8*w + 2*c], (uint2*)&h0buf[1][r16][8*w + 2*c] };
    uint2* wr1[2] = { (uint2*)&h1buf[0][r16][8*w + 2*c], (uint2*)&h1buf[1][r16][8*w + 2*c] };

    // L0 prep accumulators, two named sets rotated by the parity-unrolled loop
    f32x4 PrA = Zed, PzA = Zed, PxA = Zed;
    f32x4 PrB = Zed, PzB = Zed, PxB = Zed;

    const float* xq = nullptr;
    float2 x0v, x1v, x2v;
    if (!isL1){
        xq = x + (size_t)(b0 + r16) * (TT * II);
        float2 a  = *(const float2*)(xq + 0);
        float2 bb = *(const float2*)(xq + 2);
        float2 cc = *(const float2*)(xq + 4);
        half8 XB = mkh8(pkrtz(a.x, a.y), pkrtz(bb.x, bb.y), pkrtz(cc.x, cc.y), 0u);
        PrA = MFi(Ax[0], XB, Br);
        PzA = MFi(Ax[1], XB, Bz);
        PxA = MFi(Ax[2], XB, Bxn);
        xq += II;                              // prefetch x(1)
        x0v = *(const float2*)(xq + 0);
        x1v = *(const float2*)(xq + 2);
        x2v = *(const float2*)(xq + 4);
    }
    __syncthreads();

// L0 tick: reads issue first; x-prep (independent of reads) fills the LDS-latency
// shadow, producing Pout for the NEXT tick; h-MFMAs consume Pin from LAST tick.
#define L0TICK(P, TK, PrI, PzI, PxI, PrO, PzO, PxO) do {                            \
    half8 H0 = ldq(rd0[P]);                                                         \
    half8 H1 = ldq(rd0[P] + 16);                                                    \
    if ((TK) + 1 < TT){                                                             \
        half8 XB = mkh8(pkrtz(x0v.x, x0v.y), pkrtz(x1v.x, x1v.y),                   \
                        pkrtz(x2v.x, x2v.y), 0u);                                   \
        PrO = MFi(Ax[0], XB, Br);                                                   \
        PzO = MFi(Ax[1], XB, Bz);                                                   \
        PxO = MFi(Ax[2], XB, Bxn);                                                  \
        if ((TK) + 2 < TT){                                                         \
            xq += II;                                                               \
            x0v = *(const float2*)(xq + 0);                                         \
            x1v = *(const float2*)(xq + 2);                                         \
            x2v = *(const float2*)(xq + 4);                                         \
        }                                                                           \
    }                                                                               \
    __builtin_amdgcn_s_setprio(1);                                                  \
    f32x4 Cr  = MFi(AW[0][0], H0, PrI);  f32x4 Cz  = MFi(AW[1][0], H0, PzI);        \
    Cr        = MFi(AW[0][1], H1, Cr);   Cz        = MFi(AW[1][1], H1, Cz);         \
    f32x4 Chn = MFi(AW[2][0], H0, Bhn);  Chn       = MFi(AW[2][1], H1, Chn);        \
    __builtin_amdgcn_s_setprio(0);                                                  \
    uint2 d = gates(Cr, Cz, PxI, Chn, hp);                                          \
    *wr0[(P) ^ 1] = d;                                                              \
} while(0)

// L1 tick: 6 independent 2-chains (G-part bias-seeded, H-part zero-seeded),
// then one vector add joins Cr/Cz -> shorter serial MFMA latency.
#define L1TICK(P) do {                                                              \
    half8 G0 = ldq(rd0[P]);                                                         \
    half8 G1 = ldq(rd0[P] + 16);                                                    \
    half8 H0 = ldq(rd1[P]);                                                         \
    half8 H1 = ldq(rd1[P] + 16);                                                    \
    __builtin_amdgcn_s_setprio(1);                                                  \
    f32x4 CrG = MFi(AW[0][0], G0, Br);   f32x4 CzG = MFi(AW[1][0], G0, Bz);         \
    CrG       = MFi(AW[0][1], G1, CrG);  CzG       = MFi(AW[1][1], G1, CzG);        \
    f32x4 CrH = MFi(AW[3][0], H0, Zed);  f32x4 CzH = MFi(AW[4][0], H0, Zed);        \
    CrH       = MFi(AW[3][1], H1, CrH);  CzH       = MFi(AW[4][1], H1, CzH);        \
    f32x4 Cxn = MFi(AW[2][0], G0, Bxn);  Cxn       = MFi(AW[2][1], G1, Cxn);        \
    f32x4 Chn = MFi(AW[5][0], H0, Bhn);  Chn       = MFi(AW[5][1], H1, Chn);        \
    __builtin_amdgcn_s_setprio(0);                                                  \
    f32x4 Cr = CrG + CrH;                f32x4 Cz = CzG + CzH;                      \
    uint2 d = gates(Cr, Cz, Cxn, Chn, hp);                                          \
    *wr1[(P) ^ 1] = d;                                                              \
} while(0)

    // tick 0 (parity 0): L0 only; uses set A, produces set B
    if (!isL1) L0TICK(0, 0, PrA, PzA, PxA, PrB, PzB, PxB);
    BAR();
    #pragma unroll 1
    for (int tk = 1; tk < 255; tk += 2){
        if (!isL1) L0TICK(1, tk,     PrB, PzB, PxB, PrA, PzA, PxA); else L1TICK(1);
        BAR();
        if (!isL1) L0TICK(0, tk + 1, PrA, PzA, PxA, PrB, PzB, PxB); else L1TICK(0);
        BAR();
    }
    if (!isL1) L0TICK(1, 255, PrB, PzB, PxB, PrA, PzA, PxA); else L1TICK(1);
    BAR();
    if (isL1) L1TICK(0);        // tick 256: L1 finishes h1(255)

#undef L0TICK
#undef L1TICK

    // ---- final FC: out[b] = dot(h1_final[b], Wfc) + bfc ----
    if (isL1){
        float4 wf = *(const float4*)(Wfc + w * 16 + c * 4);
        fcpart[w * 4 + c][r16] =
            hp[0] * wf.x + hp[1] * wf.y + hp[2] * wf.z + hp[3] * wf.w;
    }
    __syncthreads();
    if (tid < MB){
        float s = bfc[0];
        #pragma unroll
        for (int k = 0; k < 16; ++k) s += fcpart[k][tid];
        out[b0 + tid] = s;
    }
}

extern "C" void kernel_launch(void* const* d_in, const int* in_sizes, int n_in,
                              void* d_out, int out_size, void* d_ws, size_t ws_size,
                              hipStream_t stream)
{
    const float* x    = (const float*)d_in[0];
    const float* Wih0 = (const float*)d_in[1];
    const float* Whh0 = (const float*)d_in[2];
    const float* bih0 = (const float*)d_in[3];
    const float* bhh0 = (const float*)d_in[4];
    const float* Wih1 = (const float*)d_in[5];
    const float* Whh1 = (const float*)d_in[6];
    const float* bih1 = (const float*)d_in[7];
    const float* bhh1 = (const float*)d_in[8];
    const float* Wfc  = (const float*)d_in[9];
    const float* bfc  = (const float*)d_in[10];
    float* out = (float*)d_out;

    dim3 grid(4096 / MB), block(512);
    gru2_v12<<<grid, block, 0, stream>>>(x, Wih0, Whh0, bih0, bhh0,
                                         Wih1, Whh1, bih1, bhh1,
                                         Wfc, bfc, out);
}

// Round 13
// 135.333 us; speedup vs baseline: 2.5907x; 1.0434x over previous
//
#include <hip/hip_runtime.h>
#include <stdint.h>

#define TT 256
#define II 6
#define HH 64
#define MB 16   // batches per block (one 16-wide MFMA N-tile)

typedef __attribute__((ext_vector_type(8))) _Float16 half8;
typedef __attribute__((ext_vector_type(4))) float f32x4;

#define K_LOG2E  1.44269504f
#define K_2LOG2E 2.88539008f

// raw barrier: LDS visibility only (x prefetch loads may span barriers)
#define BAR() asm volatile("s_waitcnt lgkmcnt(0)\n\ts_barrier" ::: "memory")

// RNE pack (init-time only)
static __device__ __forceinline__ uint32_t pkh(float a, float b){
    uint16_t ha = __builtin_bit_cast(uint16_t, (_Float16)a);
    uint16_t hb = __builtin_bit_cast(uint16_t, (_Float16)b);
    return (uint32_t)ha | ((uint32_t)hb << 16);
}
// single-instruction packed cvt (RTZ) for the hot path
static __device__ __forceinline__ uint32_t pkrtz(float a, float b){
    return __builtin_bit_cast(uint32_t, __builtin_amdgcn_cvt_pkrtz(a, b));
}
static __device__ __forceinline__ half8 mkh8(uint32_t a, uint32_t b, uint32_t c, uint32_t d){
    union { uint32_t u[4]; half8 v; } x;
    x.u[0]=a; x.u[1]=b; x.u[2]=c; x.u[3]=d;
    return x.v;
}
static __device__ __forceinline__ half8 ldq(const uint32_t* p){
    union { uint4 q; half8 v; } x;
    x.q = *(const uint4*)p;
    return x.v;
}
// functional MFMA: C-in consumed directly (no accumulator pre-copy)
static __device__ __forceinline__ f32x4 MFi(half8 A, half8 B, f32x4 C){
    return __builtin_amdgcn_mfma_f32_16x16x32_f16(A, B, C, 0, 0, 0);
}

// Pre-activations arrive pre-scaled (r,z by log2e; n rows by 2log2e):
// sigma(a)=1/(1+exp2(-C)), tanh(v)=(1-exp2(-v'))/(1+exp2(-v')); no clamp needed.
// tanh denominators rcp'd pairwise: t=rcp(d0*d1); n0=num0*(t*d1); n1=num1*(t*d0).
static __device__ __forceinline__ uint2 gates(const f32x4& Cr, const f32x4& Cz,
                                              const f32x4& Cxn, const f32x4& Chn,
                                              f32x4& hp)
{
    float num[4], den[4], zg4[4];
    #pragma unroll
    for (int q = 0; q < 4; ++q){
        float er = __builtin_amdgcn_exp2f(-Cr[q]);
        float ez = __builtin_amdgcn_exp2f(-Cz[q]);
        float pa = 1.0f + er, pb = 1.0f + ez;
        float u  = __builtin_amdgcn_rcpf(pa * pb);
        float rg = u * pb;                      // sigma(r)
        zg4[q]   = u * pa;                      // sigma(z)
        float v  = Cxn[q] + rg * Chn[q];
        float e  = __builtin_amdgcn_exp2f(-v);
        num[q] = 1.0f - e;
        den[q] = 1.0f + e;
    }
    float hn[4];
    #pragma unroll
    for (int pr = 0; pr < 2; ++pr){
        const int q0 = 2*pr, q1 = 2*pr + 1;
        float t  = __builtin_amdgcn_rcpf(den[q0] * den[q1]);
        float n0 = num[q0] * (t * den[q1]);
        float n1 = num[q1] * (t * den[q0]);
        float h0 = n0 + zg4[q0] * (hp[q0] - n0);
        float h1 = n1 + zg4[q1] * (hp[q1] - n1);
        hp[q0] = h0; hp[q1] = h1;
        hn[q0] = h0; hn[q1] = h1;
    }
    return make_uint2(pkrtz(hn[0], hn[1]), pkrtz(hn[2], hn[3]));
}

__global__ __launch_bounds__(512, 2)
void gru2_v13(const float* __restrict__ x,
              const float* __restrict__ Wih0, const float* __restrict__ Whh0,
              const float* __restrict__ bih0, const float* __restrict__ bhh0,
              const float* __restrict__ Wih1, const float* __restrict__ Whh1,
              const float* __restrict__ bih1, const float* __restrict__ bhh1,
              const float* __restrict__ Wfc,  const float* __restrict__ bfc,
              float* __restrict__ out)
{
    __shared__ uint32_t h0buf[2][MB][36];   // [parity][batch][h/2 dwords + pad]
    __shared__ uint32_t h1buf[2][MB][36];
    __shared__ float    fcpart[16][MB];

    const int tid  = threadIdx.x;
    const int lane = tid & 63;
    const int wg   = tid >> 6;       // 0..7
    const int isL1 = (wg >= 4);      // waves 4..7 run layer 1 (lagged one tick)
    const int w    = wg & 3;         // 16-row tile within each gate
    const int c    = lane >> 4;      // k-group / C row-group
    const int r16  = lane & 15;      // batch col
    const int b0   = blockIdx.x * MB;

    for (int i = tid; i < 2 * MB * 36; i += 512){
        (&h0buf[0][0][0])[i] = 0u;
        (&h1buf[0][0][0])[i] = 0u;
    }

    // ---- A-fragments (fp16, pre-scaled by {log2e, log2e, 2log2e}) ----
    const float gsc[3] = { K_LOG2E, K_LOG2E, K_2LOG2E };
    half8 AW[6][2];
    {
        const float* M0 = isL1 ? Wih1 : Whh0;
        #pragma unroll
        for (int m = 0; m < 6; ++m){
            if (m >= 3 && !isL1) continue;
            const float* Wb = (m < 3) ? M0 : Whh1;
            const float s = gsc[m % 3];
            const float* rowp = Wb + (size_t)((m % 3) * 64 + w * 16 + r16) * HH;
            #pragma unroll
            for (int cw = 0; cw < 2; ++cw){
                const float* pp = rowp + cw * 32 + c * 8;
                AW[m][cw] = mkh8(pkh(s*pp[0], s*pp[1]), pkh(s*pp[2], s*pp[3]),
                                 pkh(s*pp[4], s*pp[5]), pkh(s*pp[6], s*pp[7]));
            }
        }
    }
    half8 Ax[3];
    #pragma unroll
    for (int g = 0; g < 3; ++g){
        if (c == 0 && !isL1){
            const float s = gsc[g];
            const float* rowp = Wih0 + (size_t)(g * 64 + w * 16 + r16) * II;
            Ax[g] = mkh8(pkh(s*rowp[0], s*rowp[1]), pkh(s*rowp[2], s*rowp[3]),
                         pkh(s*rowp[4], s*rowp[5]), 0u);
        } else {
            Ax[g] = mkh8(0u, 0u, 0u, 0u);
        }
    }

    // biases (pre-scaled): row = g*64 + w*16 + 4c + q
    const float* bi = isL1 ? bih1 : bih0;
    const float* bh = isL1 ? bhh1 : bhh0;
    const int rq0 = w * 16 + c * 4;
    f32x4 Br, Bz, Bxn, Bhn;
    #pragma unroll
    for (int q = 0; q < 4; ++q){
        Br[q]  = K_LOG2E  * (bi[      rq0 + q] + bh[      rq0 + q]);
        Bz[q]  = K_LOG2E  * (bi[ 64 + rq0 + q] + bh[ 64 + rq0 + q]);
        Bxn[q] = K_2LOG2E *  bi[128 + rq0 + q];
        Bhn[q] = K_2LOG2E *  bh[128 + rq0 + q];
    }

    f32x4 hp = {0.f, 0.f, 0.f, 0.f};   // fp32 carry of own h slice

    // hoisted per-parity LDS pointers
    const uint32_t* rd0[2] = { &h0buf[0][r16][4*c], &h0buf[1][r16][4*c] };
    const uint32_t* rd1[2] = { &h1buf[0][r16][4*c], &h1buf[1][r16][4*c] };
    uint2* wr0[2] = { (uint2*)&h0buf[0][r16][8*w + 2*c], (uint2*)&h0buf[1][r16][8*w + 2*c] };
    uint2* wr1[2] = { (uint2*)&h1buf[0][r16][8*w + 2*c], (uint2*)&h1buf[1][r16][8*w + 2*c] };

    // L0 carried state: prep accumulators (bias consumed via MFMA C-in, no copies)
    f32x4 Pr = {0,0,0,0}, Pz = {0,0,0,0}, Pxn = {0,0,0,0};

    const float* xq = nullptr;
    float2 x0v, x1v, x2v;
    if (!isL1){
        xq = x + (size_t)(b0 + r16) * (TT * II);
        float2 a  = *(const float2*)(xq + 0);
        float2 bb = *(const float2*)(xq + 2);
        float2 cc = *(const float2*)(xq + 4);
        half8 XB = mkh8(pkrtz(a.x, a.y), pkrtz(bb.x, bb.y), pkrtz(cc.x, cc.y), 0u);
        Pr  = MFi(Ax[0], XB, Br);
        Pz  = MFi(Ax[1], XB, Bz);
        Pxn = MFi(Ax[2], XB, Bxn);
        xq += II;                              // prefetch x(1)
        x0v = *(const float2*)(xq + 0);
        x1v = *(const float2*)(xq + 2);
        x2v = *(const float2*)(xq + 4);
    }
    __syncthreads();

#define L0TICK(P, TK) do {                                                          \
    half8 H0 = ldq(rd0[P]);                                                         \
    half8 H1 = ldq(rd0[P] + 16);                                                    \
    __builtin_amdgcn_s_setprio(1);                                                  \
    f32x4 Cr  = MFi(AW[0][0], H0, Pr);   f32x4 Cz  = MFi(AW[1][0], H0, Pz);         \
    Cr        = MFi(AW[0][1], H1, Cr);   Cz        = MFi(AW[1][1], H1, Cz);         \
    f32x4 Chn = MFi(AW[2][0], H0, Bhn);  Chn       = MFi(AW[2][1], H1, Chn);        \
    __builtin_amdgcn_s_setprio(0);                                                  \
    uint2 d = gates(Cr, Cz, Pxn, Chn, hp);                                          \
    *wr0[(P) ^ 1] = d;                                                              \
    if ((TK) + 1 < TT){   /* prep next tick: x-MFMAs consume biases as C-in */      \
        half8 XB = mkh8(pkrtz(x0v.x, x0v.y), pkrtz(x1v.x, x1v.y),                   \
                        pkrtz(x2v.x, x2v.y), 0u);                                   \
        Pr  = MFi(Ax[0], XB, Br);                                                   \
        Pz  = MFi(Ax[1], XB, Bz);                                                   \
        Pxn = MFi(Ax[2], XB, Bxn);                                                  \
        if ((TK) + 2 < TT){                                                         \
            xq += II;                                                               \
            x0v = *(const float2*)(xq + 0);                                         \
            x1v = *(const float2*)(xq + 2);                                         \
            x2v = *(const float2*)(xq + 4);                                         \
        }                                                                           \
    }                                                                               \
} while(0)

#define L1TICK(P) do {                                                              \
    half8 G0 = ldq(rd0[P]);                                                         \
    half8 G1 = ldq(rd0[P] + 16);                                                    \
    half8 H0 = ldq(rd1[P]);                                                         \
    half8 H1 = ldq(rd1[P] + 16);                                                    \
    __builtin_amdgcn_s_setprio(1);                                                  \
    f32x4 Cr  = MFi(AW[0][0], G0, Br);   f32x4 Cz  = MFi(AW[1][0], G0, Bz);         \
    Cr        = MFi(AW[0][1], G1, Cr);   Cz        = MFi(AW[1][1], G1, Cz);         \
    Cr        = MFi(AW[3][0], H0, Cr);   Cz        = MFi(AW[4][0], H0, Cz);         \
    Cr        = MFi(AW[3][1], H1, Cr);   Cz        = MFi(AW[4][1], H1, Cz);         \
    f32x4 Cxn = MFi(AW[2][0], G0, Bxn);  Cxn       = MFi(AW[2][1], G1, Cxn);        \
    f32x4 Chn = MFi(AW[5][0], H0, Bhn);  Chn       = MFi(AW[5][1], H1, Chn);        \
    __builtin_amdgcn_s_setprio(0);                                                  \
    uint2 d = gates(Cr, Cz, Cxn, Chn, hp);                                          \
    *wr1[(P) ^ 1] = d;                                                              \
} while(0)

    // tick 0: L0 only
    if (!isL1) L0TICK(0, 0);
    BAR();
    #pragma unroll 1
    for (int tk = 1; tk < 255; tk += 2){
        if (!isL1) L0TICK(1, tk); else L1TICK(1);
        BAR();
        if (!isL1) L0TICK(0, tk + 1); else L1TICK(0);
        BAR();
    }
    if (!isL1) L0TICK(1, 255); else L1TICK(1);
    BAR();
    if (isL1) L1TICK(0);        // tick 256: L1 finishes h1(255)

#undef L0TICK
#undef L1TICK

    // ---- final FC: out[b] = dot(h1_final[b], Wfc) + bfc ----
    if (isL1){
        float4 wf = *(const float4*)(Wfc + w * 16 + c * 4);
        fcpart[w * 4 + c][r16] =
            hp[0] * wf.x + hp[1] * wf.y + hp[2] * wf.z + hp[3] * wf.w;
    }
    __syncthreads();
    if (tid < MB){
        float s = bfc[0];
        #pragma unroll
        for (int k = 0; k < 16; ++k) s += fcpart[k][tid];
        out[b0 + tid] = s;
    }
}

extern "C" void kernel_launch(void* const* d_in, const int* in_sizes, int n_in,
                              void* d_out, int out_size, void* d_ws, size_t ws_size,
                              hipStream_t stream)
{
    const float* x    = (const float*)d_in[0];
    const float* Wih0 = (const float*)d_in[1];
    const float* Whh0 = (const float*)d_in[2];
    const float* bih0 = (const float*)d_in[3];
    const float* bhh0 = (const float*)d_in[4];
    const float* Wih1 = (const float*)d_in[5];
    const float* Whh1 = (const float*)d_in[6];
    const float* bih1 = (const float*)d_in[7];
    const float* bhh1 = (const float*)d_in[8];
    const float* Wfc  = (const float*)d_in[9];
    const float* bfc  = (const float*)d_in[10];
    float* out = (float*)d_out;

    dim3 grid(4096 / MB), block(512);
    gru2_v13<<<grid, block, 0, stream>>>(x, Wih0, Whh0, bih0, bhh0,
                                         Wih1, Whh1, bih1, bhh1,
                                         Wfc, bfc, out);
}